// Round 2
// baseline (982.854 us; speedup 1.0000x reference)
//
#include <hip/hip_runtime.h>
#include <cstdint>

#define BH    64
#define NSEQ  4096
#define DH    64
#define MF    256
#define RT    128
#define EPS   1e-6f

typedef float f32;
typedef __attribute__((ext_vector_type(4))) float f32x4;

__device__ __forceinline__ float gelu_eps(float x) {
    return 0.5f * x * (1.0f + erff(x * 0.70710678118654752f)) + EPS;
}

// ws layout: [ctx: 64*256*64 f32][ksum: 64*256 f32] = 4,210,688 floats
#define CTX_FLOATS (BH * MF * 64)
#define WS_FLOATS  (CTX_FLOATS + BH * MF)

__global__ void zero_ws_kernel(f32x4* __restrict__ p) {
    int i = blockIdx.x * 256 + threadIdx.x;   // grid sized exactly
    p[i] = (f32x4){0.f, 0.f, 0.f, 0.f};
}

// ---------------------------------------------------------------------------
// kside: for each (bh, chunk-group of 4x128 rows):
//   kp = gelu(K@P^T)+eps ; ctx[f][e] += kp^T@V ; ksum[f] += col-sums(kp)
// ---------------------------------------------------------------------------
__global__ __launch_bounds__(256) void kside_kernel(
    const f32* __restrict__ Kg_, const f32* __restrict__ Vg_,
    const f32* __restrict__ Pg_, f32* __restrict__ ctx_ws,
    f32* __restrict__ ksum_ws)
{
    __shared__ f32x4 sV4[RT * 16];   // [row][e-quad] packed, 32 KB
    __shared__ f32x4 kp4[RT * 16];   // [row][feat-quad ^ (row&15)], 32 KB
    __shared__ f32x4 sP4[64 * 16];   // [d][feat-quad ^ (d&15)], 16 KB

    const int tid = threadIdx.x;
    const int bh  = blockIdx.x >> 3;
    const int cg  = blockIdx.x & 7;
    const int rg  = tid >> 3, fg = tid & 7;    // S-GEMM: 32 row-groups x 8 feat-octets
    const int fq  = tid & 15, eg = tid >> 4;   // ctx-GEMM: 16 f-quads x 16 e-quads
    const size_t bhbase = (size_t)bh * NSEQ;

    f32x4 ctxacc[4][4];   // [f-chunk][fi] : vec over 4 e
    f32x4 ksacc[4];
    #pragma unroll
    for (int f = 0; f < 4; ++f) {
        ksacc[f] = (f32x4){0.f, 0.f, 0.f, 0.f};
        #pragma unroll
        for (int fi = 0; fi < 4; ++fi) ctxacc[f][fi] = (f32x4){0.f, 0.f, 0.f, 0.f};
    }

    for (int c = 0; c < 4; ++c) {
        const int rowbase = cg * 512 + c * 128;
        __syncthreads();  // prev ctx-GEMM readers of sV done
        const f32x4* Vg = (const f32x4*)(Vg_ + (bhbase + rowbase) * DH);
        #pragma unroll
        for (int p = 0; p < 8; ++p) sV4[tid + p * 256] = Vg[tid + p * 256];

        const f32* Kg = Kg_ + (bhbase + rowbase) * DH;

        #pragma unroll
        for (int f = 0; f < 4; ++f) {
            // stage P^T (transposed, swizzled). Safe: nobody reads sP4 now.
            {
                const f32x4* Pg = (const f32x4*)(Pg_ + (size_t)f * 64 * DH);
                f32* base = (f32*)sP4;
                #pragma unroll
                for (int p = 0; p < 4; ++p) {
                    int m2 = tid + p * 256;        // 0..1023
                    int feat = m2 >> 4, dq = m2 & 15;
                    f32x4 val = Pg[m2];            // proj[f*64+feat][dq*4..+3]
                    #pragma unroll
                    for (int jj = 0; jj < 4; ++jj) {
                        int d = dq * 4 + jj;
                        base[d * 64 + (((feat >> 2) ^ (d & 15)) << 2) + (feat & 3)] = val[jj];
                    }
                }
            }
            __syncthreads();  // sP ready; prev-f ctx-GEMM (kp readers) done

            // S-GEMM: rows rg*4..+3 x feats fg*8..+7, K-dim = 64
            f32x4 s0[4], s1[4];
            #pragma unroll
            for (int r = 0; r < 4; ++r) {
                s0[r] = (f32x4){0.f, 0.f, 0.f, 0.f};
                s1[r] = (f32x4){0.f, 0.f, 0.f, 0.f};
            }
            #pragma unroll 4
            for (int kb = 0; kb < 16; ++kb) {
                f32x4 a[4];
                #pragma unroll
                for (int r = 0; r < 4; ++r)
                    a[r] = *(const f32x4*)(Kg + (size_t)(rg * 4 + r) * DH + kb * 4);
                #pragma unroll
                for (int kk = 0; kk < 4; ++kk) {
                    int d = kb * 4 + kk;
                    f32x4 b0 = sP4[d * 16 + ((fg * 2)     ^ (d & 15))];
                    f32x4 b1 = sP4[d * 16 + ((fg * 2 + 1) ^ (d & 15))];
                    #pragma unroll
                    for (int r = 0; r < 4; ++r) {
                        s0[r] += a[r][kk] * b0;
                        s1[r] += a[r][kk] * b1;
                    }
                }
            }
            // gelu + swizzled store
            #pragma unroll
            for (int r = 0; r < 4; ++r) {
                int row = rg * 4 + r;
                f32x4 g0, g1;
                #pragma unroll
                for (int i = 0; i < 4; ++i) { g0[i] = gelu_eps(s0[r][i]); g1[i] = gelu_eps(s1[r][i]); }
                kp4[row * 16 + ((fg * 2)     ^ (row & 15))] = g0;
                kp4[row * 16 + ((fg * 2 + 1) ^ (row & 15))] = g1;
            }
            __syncthreads();  // kp ready

            // ctx-GEMM: feats fq*4..+3 x e eg*4..+3, reduce over 128 rows
            #pragma unroll 4
            for (int rb = 0; rb < 32; ++rb) {
                f32x4 a4[4], b4[4];
                #pragma unroll
                for (int rr = 0; rr < 4; ++rr) {
                    int row = rb * 4 + rr;
                    a4[rr] = kp4[row * 16 + (fq ^ (row & 15))];
                    b4[rr] = sV4[row * 16 + eg];
                }
                #pragma unroll
                for (int rr = 0; rr < 4; ++rr) {
                    #pragma unroll
                    for (int fi = 0; fi < 4; ++fi)
                        ctxacc[f][fi] += a4[rr][fi] * b4[rr];
                }
                if (eg == 0) {
                    #pragma unroll
                    for (int rr = 0; rr < 4; ++rr) ksacc[f] += a4[rr];
                }
            }
            // no barrier here: next-f sP staging doesn't touch kp/sV; the
            // pre-S-GEMM barrier protects kp stores.
        }
    }

    // accumulate partials into global ws
    #pragma unroll
    for (int f = 0; f < 4; ++f) {
        f32* cb = ctx_ws + ((size_t)bh * MF + f * 64 + fq * 4) * 64 + eg * 4;
        #pragma unroll
        for (int fi = 0; fi < 4; ++fi)
            #pragma unroll
            for (int ei = 0; ei < 4; ++ei)
                atomicAdd(cb + (size_t)fi * 64 + ei, ctxacc[f][fi][ei]);
        if (eg == 0) {
            f32* kb_ = ksum_ws + (size_t)bh * MF + f * 64 + fq * 4;
            #pragma unroll
            for (int fi = 0; fi < 4; ++fi) atomicAdd(kb_ + fi, ksacc[f][fi]);
        }
    }
}

// ---------------------------------------------------------------------------
// qside: qp = gelu(Q@P^T)+eps ; num = qp@ctx ; den = qp.ksum ; out = num/den
// ---------------------------------------------------------------------------
__global__ __launch_bounds__(256) void qside_kernel(
    const f32* __restrict__ Qg_, const f32* __restrict__ Pg_,
    const f32* __restrict__ ctx_ws, const f32* __restrict__ ksum_ws,
    f32* __restrict__ out)
{
    __shared__ f32x4 qp4[RT * 16];   // 32 KB, swizzled
    __shared__ f32x4 sU4[64 * 16];   // 16 KB, union: P^T then ctx-chunk
    __shared__ f32x4 sks4[64];       // 1 KB: all 256 ksum

    const int tid   = threadIdx.x;
    const int bh    = blockIdx.x >> 5;
    const int chunk = blockIdx.x & 31;
    const int rg = tid >> 3, fg = tid & 7;
    const size_t bhbase  = (size_t)bh * NSEQ;
    const int    rowbase = chunk * 128;

    if (tid < 64) sks4[tid] = ((const f32x4*)(ksum_ws + (size_t)bh * MF))[tid];

    const f32* Qg = Qg_ + (bhbase + rowbase) * DH;

    f32x4 num[4][2];
    float den[4] = {0.f, 0.f, 0.f, 0.f};
    #pragma unroll
    for (int r = 0; r < 4; ++r) { num[r][0] = (f32x4){0.f,0.f,0.f,0.f}; num[r][1] = (f32x4){0.f,0.f,0.f,0.f}; }

    for (int f = 0; f < 4; ++f) {
        __syncthreads();  // prev num-GEMM readers of sU/qp done (also covers sks stage)
        {   // stage P^T swizzled
            const f32x4* Pg = (const f32x4*)(Pg_ + (size_t)f * 64 * DH);
            f32* base = (f32*)sU4;
            #pragma unroll
            for (int p = 0; p < 4; ++p) {
                int m2 = tid + p * 256;
                int feat = m2 >> 4, dq = m2 & 15;
                f32x4 val = Pg[m2];
                #pragma unroll
                for (int jj = 0; jj < 4; ++jj) {
                    int d = dq * 4 + jj;
                    base[d * 64 + (((feat >> 2) ^ (d & 15)) << 2) + (feat & 3)] = val[jj];
                }
            }
        }
        __syncthreads();

        // S-GEMM (Q @ P^T)
        f32x4 s0[4], s1[4];
        #pragma unroll
        for (int r = 0; r < 4; ++r) {
            s0[r] = (f32x4){0.f, 0.f, 0.f, 0.f};
            s1[r] = (f32x4){0.f, 0.f, 0.f, 0.f};
        }
        #pragma unroll 4
        for (int kb = 0; kb < 16; ++kb) {
            f32x4 a[4];
            #pragma unroll
            for (int r = 0; r < 4; ++r)
                a[r] = *(const f32x4*)(Qg + (size_t)(rg * 4 + r) * DH + kb * 4);
            #pragma unroll
            for (int kk = 0; kk < 4; ++kk) {
                int d = kb * 4 + kk;
                f32x4 b0 = sU4[d * 16 + ((fg * 2)     ^ (d & 15))];
                f32x4 b1 = sU4[d * 16 + ((fg * 2 + 1) ^ (d & 15))];
                #pragma unroll
                for (int r = 0; r < 4; ++r) {
                    s0[r] += a[r][kk] * b0;
                    s1[r] += a[r][kk] * b1;
                }
            }
        }
        #pragma unroll
        for (int r = 0; r < 4; ++r) {
            int row = rg * 4 + r;
            f32x4 g0, g1;
            #pragma unroll
            for (int i = 0; i < 4; ++i) { g0[i] = gelu_eps(s0[r][i]); g1[i] = gelu_eps(s1[r][i]); }
            qp4[row * 16 + ((fg * 2)     ^ (row & 15))] = g0;
            qp4[row * 16 + ((fg * 2 + 1) ^ (row & 15))] = g1;
        }
        __syncthreads();  // S-GEMM sU reads + qp writes complete

        {   // stage ctx chunk into sU (swizzled)
            const f32x4* Cg = (const f32x4*)(ctx_ws + ((size_t)bh * MF + f * 64) * 64);
            #pragma unroll
            for (int p = 0; p < 4; ++p) {
                int m2 = tid + p * 256;
                int feat = m2 >> 4, eq = m2 & 15;
                sU4[feat * 16 + (eq ^ (feat & 15))] = Cg[m2];
            }
        }
        __syncthreads();

        // num-GEMM: rows rg*4..+3 x e fg*8..+7, reduce over 64 feats
        #pragma unroll 4
        for (int kb = 0; kb < 16; ++kb) {
            f32x4 a[4];
            #pragma unroll
            for (int r = 0; r < 4; ++r) {
                int row = rg * 4 + r;
                a[r] = qp4[row * 16 + (kb ^ (row & 15))];
            }
            f32x4 kv = sks4[f * 16 + kb];
            #pragma unroll
            for (int kk = 0; kk < 4; ++kk) {
                int k = kb * 4 + kk;
                f32x4 b0 = sU4[k * 16 + ((fg * 2)     ^ (k & 15))];
                f32x4 b1 = sU4[k * 16 + ((fg * 2 + 1) ^ (k & 15))];
                #pragma unroll
                for (int r = 0; r < 4; ++r) {
                    num[r][0] += a[r][kk] * b0;
                    num[r][1] += a[r][kk] * b1;
                }
            }
            #pragma unroll
            for (int r = 0; r < 4; ++r)
                den[r] += a[r][0] * kv[0] + a[r][1] * kv[1] + a[r][2] * kv[2] + a[r][3] * kv[3];
        }
    }

    #pragma unroll
    for (int r = 0; r < 4; ++r) {
        int row = rg * 4 + r;
        float dinv = 1.0f / den[r];
        f32x4 o0 = num[r][0] * dinv;
        f32x4 o1 = num[r][1] * dinv;
        f32* ob = out + (size_t)(bhbase + rowbase + row) * DH + fg * 8;
        *(f32x4*)(ob)     = o0;
        *(f32x4*)(ob + 4) = o1;
    }
}

extern "C" void kernel_launch(void* const* d_in, const int* in_sizes, int n_in,
                              void* d_out, int out_size, void* d_ws, size_t ws_size,
                              hipStream_t stream) {
    const f32* q    = (const f32*)d_in[0];
    const f32* k    = (const f32*)d_in[1];
    const f32* v    = (const f32*)d_in[2];
    const f32* proj = (const f32*)d_in[3];
    f32* out     = (f32*)d_out;
    f32* ctx_ws  = (f32*)d_ws;
    f32* ksum_ws = ctx_ws + CTX_FLOATS;

    const int nzero = WS_FLOATS / 4;  // 1,052,672 f32x4, exact multiple of 256
    hipLaunchKernelGGL(zero_ws_kernel, dim3(nzero / 256), dim3(256), 0, stream,
                       (f32x4*)d_ws);
    hipLaunchKernelGGL(kside_kernel, dim3(BH * 8), dim3(256), 0, stream,
                       k, v, proj, ctx_ws, ksum_ws);
    hipLaunchKernelGGL(qside_kernel, dim3(BH * 32), dim3(256), 0, stream,
                       q, proj, ctx_ws, ksum_ws, out);
}